// Round 15
// baseline (353.846 us; speedup 1.0000x reference)
//
#include <hip/hip_runtime.h>

using short8 = __attribute__((ext_vector_type(8))) short;
using f32x4  = __attribute__((ext_vector_type(4))) float;
typedef unsigned short ushort_t;
typedef unsigned int u32;

#define T_TOK 2048
#define DH 2048
#define DE 1408
#define DS 2816
#define GU_NB 440   // gateup 256x128 tiles, multiple of 8
#define DN_NB 256   // down 256x256 tiles, multiple of 8

#define NGEc 23068672UL
#define NGSc 5767168UL
#define NXc  4194304UL
#define PA_CVT_BLOCKS 3584    // grid-stride persistent cvt blocks
#define PB_CVT_BLOCKS 7040

#define FENCE() asm volatile("" ::: "memory")

__device__ __forceinline__ unsigned short f2bf(float f) {
  unsigned u = __float_as_uint(f);
  u += 0x7FFF + ((u >> 16) & 1);
  return (unsigned short)(u >> 16);
}

__device__ __forceinline__ void gl_lds16(const void* g, void* l) {
  __builtin_amdgcn_global_load_lds((const __attribute__((address_space(1))) u32*)g,
                                   (__attribute__((address_space(3))) u32*)l, 16, 0, 0);
}

__device__ __forceinline__ short8 pack_bf8(float4 a, float4 b) {
  short8 o;
  o[0] = (short)f2bf(a.x); o[1] = (short)f2bf(a.y);
  o[2] = (short)f2bf(a.z); o[3] = (short)f2bf(a.w);
  o[4] = (short)f2bf(b.x); o[5] = (short)f2bf(b.y);
  o[6] = (short)f2bf(b.z); o[7] = (short)f2bf(b.w);
  return o;
}

// ---------------- phase A: router || grid-stride cvt Wg_e,Wu_e,Wg_s,Wu_s,x ----------------
__global__ void phaseA_kernel(const float* __restrict__ x, const float* __restrict__ gW,
                              int* __restrict__ counts, int* __restrict__ tok_e,
                              int* __restrict__ tok_slot, float* __restrict__ tok_w,
                              const float* __restrict__ Wg_e, const float* __restrict__ Wu_e,
                              const float* __restrict__ Wg_s, const float* __restrict__ Wu_s,
                              ushort_t* wbg_e, ushort_t* wbu_e,
                              ushort_t* wbg_s, ushort_t* wbu_s, ushort_t* xb) {
  int b = blockIdx.x;
  int tid = threadIdx.x;
  if (b < 512) {
    int wid = tid >> 6, lane = tid & 63;
    int t = b * 4 + wid;
    float acc[8] = {0.f,0.f,0.f,0.f,0.f,0.f,0.f,0.f};
    const float* xt = x + (size_t)t * DH;
    for (int i = lane; i < DH; i += 64) {
      float xv = xt[i];
#pragma unroll
      for (int e = 0; e < 8; e++) acc[e] += xv * gW[e * DH + i];
    }
#pragma unroll
    for (int e = 0; e < 8; e++) {
#pragma unroll
      for (int off = 32; off > 0; off >>= 1) acc[e] += __shfl_xor(acc[e], off);
    }
    if (lane == 0) {
      float mx = acc[0];
      for (int e = 1; e < 8; e++) mx = fmaxf(mx, acc[e]);
      float p[8], se = 0.f;
      for (int e = 0; e < 8; e++) { p[e] = __expf(acc[e] - mx); se += p[e]; }
      for (int e = 0; e < 8; e++) p[e] /= se;
      int i1 = 0;
      for (int e = 1; e < 8; e++) if (p[e] > p[i1]) i1 = e;
      int i2 = (i1 == 0) ? 1 : 0;
      for (int e = 0; e < 8; e++) if (e != i1 && p[e] > p[i2]) i2 = e;
      int s1 = atomicAdd(&counts[i1], 1);
      int s2 = atomicAdd(&counts[i2], 1);
      tok_e[2 * t] = i1;     tok_e[2 * t + 1] = i2;
      tok_slot[2 * t] = s1;  tok_slot[2 * t + 1] = s2;
      tok_w[2 * t] = p[i1];  tok_w[2 * t + 1] = p[i2];
    }
    return;
  }
  // grid-stride cvt over 61,865,984 elems (7,733,248 vec8)
  const size_t NVEC = (2 * NGEc + 2 * NGSc + NXc) / 8;
  size_t v0 = (size_t)(b - 512) * 256 + tid;
  const size_t stride = (size_t)PA_CVT_BLOCKS * 256;
  for (size_t v = v0; v < NVEC; v += stride) {
    size_t i = v * 8;
    const float* s; ushort_t* d; size_t o;
    if      (i < NGEc)                    { s = Wg_e; d = wbg_e; o = i; }
    else if (i < 2 * NGEc)                { s = Wu_e; d = wbu_e; o = i - NGEc; }
    else if (i < 2 * NGEc + NGSc)         { s = Wg_s; d = wbg_s; o = i - 2 * NGEc; }
    else if (i < 2 * NGEc + 2 * NGSc)     { s = Wu_s; d = wbu_s; o = i - 2 * NGEc - NGSc; }
    else                                  { s = x;    d = xb;    o = i - 2 * NGEc - 2 * NGSc; }
    float4 a = *(const float4*)(s + o);
    float4 bb = *(const float4*)(s + o + 4);
    __builtin_nontemporal_store(pack_bf8(a, bb), (short8*)(d + o));
  }
}

// ---------------- prefix ----------------
__global__ void prefix_assign_kernel(const int* __restrict__ counts, int* __restrict__ ebase,
                                     int* __restrict__ gu_off, int* __restrict__ dn_off,
                                     const int* __restrict__ tok_e, int* __restrict__ tok_slot,
                                     int* __restrict__ slot2tok) {
  __shared__ int sbase[8];
  if (threadIdx.x == 0) {
    int a = 0;
    for (int e = 0; e < 8; e++) { sbase[e] = a; ebase[e] = a; a += counts[e]; }
    int g = 0, d = 0;
    for (int z = 0; z < 8; z++) {
      gu_off[z] = g; dn_off[z] = d;
      int Lg = (counts[z] + 255) >> 8;
      g += Lg * 11;
      int Ld = (counts[z] + 255) >> 8;
      d += Ld * 8;
    }
    gu_off[8] = g; g += 88;
    gu_off[9] = g; g += 88;
    gu_off[10] = g;
    dn_off[8] = d; d += 64;
    dn_off[9] = d;
  }
  __syncthreads();
  for (int idx = threadIdx.x; idx < T_TOK * 2; idx += blockDim.x) {
    int e = tok_e[idx];
    int g = sbase[e] + tok_slot[idx];
    tok_slot[idx] = g;
    slot2tok[g] = idx >> 1;
  }
}

// ---------------- phase B: gateup 256x128 8-wave 2-phase (R13 body) || cvt Wd ----------------
__global__ __launch_bounds__(512, 1) void phaseB_kernel(
    const ushort_t* __restrict__ xb, const int* __restrict__ counts,
    const int* __restrict__ ebase, const int* __restrict__ gu_off,
    const int* __restrict__ slot2tok,
    const ushort_t* __restrict__ Wbg_e, const ushort_t* __restrict__ Wbu_e,
    const ushort_t* __restrict__ Wbg_s, const ushort_t* __restrict__ Wbu_s,
    ushort_t* __restrict__ h_r, ushort_t* __restrict__ h_s,
    const float* __restrict__ Wd_e, const float* __restrict__ Wd_s,
    ushort_t* wbd_e, ushort_t* wbd_s) {
  extern __shared__ char smem[];   // 128KB: A[2][32K] @0 | Bg[2][16K] @64K | Bu[2][16K] @96K
  int tid = threadIdx.x;
  if (blockIdx.x >= GU_NB) {
    size_t i = (size_t)(blockIdx.x - GU_NB) * 4096 + (size_t)tid * 8;
    const float* s; ushort_t* d; size_t o;
    if (i < NGEc) { s = Wd_e; d = wbd_e; o = i; }
    else          { s = Wd_s; d = wbd_s; o = i - NGEc; }
    float4 a = *(const float4*)(s + o);
    float4 bb = *(const float4*)(s + o + 4);
    __builtin_nontemporal_store(pack_bf8(a, bb), (short8*)(d + o));
    return;
  }
  int b = blockIdx.x;
  int c = (b & 7) * (GU_NB >> 3) + (b >> 3);
  int off[11];
#pragma unroll
  for (int zz = 0; zz < 11; zz++) off[zz] = gu_off[zz];
  if (c >= off[10]) return;
  int z = 0;
#pragma unroll
  for (int zz = 1; zz < 10; zz++) if (c >= off[zz]) z = zz;
  int cz = c - off[z];

  bool routed = (z < 8);
  int cnt, gbase, Lm;
  const ushort_t *Bg, *Bu;
  if (routed) {
    cnt = counts[z]; gbase = ebase[z];
    Lm = (cnt + 255) >> 8;
    Bg = Wbg_e + (size_t)z * DE * DH;
    Bu = Wbu_e + (size_t)z * DE * DH;
  } else {
    cnt = T_TOK; gbase = 0; Lm = 8;
    Bg = Wbg_s + (size_t)(z - 8) * 1408 * DH;
    Bu = Wbu_s + (size_t)(z - 8) * 1408 * DH;
  }
  int mt = cz % Lm, y = cz / Lm;
  int m0 = mt * 256, n0 = y * 128;

  int lane = tid & 63, w = tid >> 6;
  int lr = lane & 15, lk = lane >> 4;
  int wm = w >> 1, wn = w & 1;

  const ushort_t* asrc[4];
  int adst[4];
#pragma unroll
  for (int j = 0; j < 4; j++) {
    int r = (w * 4 + j) * 8 + (lane >> 3);
    int lrow = m0 + r;
    int tok = routed ? ((lrow < cnt) ? slot2tok[gbase + lrow] : 0) : lrow;
    int cs = (lane & 7) ^ (r & 7);
    asrc[j] = xb + (size_t)tok * DH + cs * 8;
    adst[j] = (w * 4 + j) * 1024;
  }
  const ushort_t* gsrc[2];
  const ushort_t* usrc[2];
  int wdst[2];
#pragma unroll
  for (int j = 0; j < 2; j++) {
    int r = (w * 2 + j) * 8 + (lane >> 3);
    int cs = (lane & 7) ^ (r & 7);
    gsrc[j] = Bg + (size_t)(n0 + r) * DH + cs * 8;
    usrc[j] = Bu + (size_t)(n0 + r) * DH + cs * 8;
    wdst[j] = (w * 2 + j) * 1024;
  }

  f32x4 accg[4][4] = {};
  f32x4 accu[4][4] = {};

#define GU_STAGE(buf, k0)                                             \
  {                                                                   \
    char* ab = smem + (buf) * 32768;                                  \
    char* gb = smem + 65536 + (buf) * 16384;                          \
    char* ub = smem + 98304 + (buf) * 16384;                          \
    _Pragma("unroll")                                                 \
    for (int j = 0; j < 4; j++) gl_lds16(asrc[j] + (k0), ab + adst[j]); \
    _Pragma("unroll")                                                 \
    for (int j = 0; j < 2; j++) {                                     \
      gl_lds16(gsrc[j] + (k0), gb + wdst[j]);                         \
      gl_lds16(usrc[j] + (k0), ub + wdst[j]);                         \
    }                                                                 \
  }

  const int nt = DH >> 6;   // 32
  GU_STAGE(0, 0);
  __syncthreads();
  int cur = 0;
  for (int t = 0; t < nt; t++) {
    if (t + 1 < nt) GU_STAGE(cur ^ 1, (t + 1) * 64);
    const char* ab = smem + cur * 32768;
    const char* gb = smem + 65536 + cur * 16384;
    const char* ub = smem + 98304 + cur * 16384;
    short8 af[4][2], bg[4][2], bu[4][2];
#pragma unroll
    for (int m = 0; m < 4; m++) {
#pragma unroll
      for (int ks = 0; ks < 2; ks++) {
        int rr = wm * 64 + m * 16 + lr;
        af[m][ks] = *(const short8*)(ab + rr * 128 + ((ks * 64 + lk * 16) ^ ((rr & 7) << 4)));
      }
    }
#pragma unroll
    for (int n = 0; n < 4; n++) {
#pragma unroll
      for (int ks = 0; ks < 2; ks++) {
        int cc = wn * 64 + n * 16 + lr;
        bg[n][ks] = *(const short8*)(gb + cc * 128 + ((ks * 64 + lk * 16) ^ ((cc & 7) << 4)));
        bu[n][ks] = *(const short8*)(ub + cc * 128 + ((ks * 64 + lk * 16) ^ ((cc & 7) << 4)));
      }
    }
    __builtin_amdgcn_s_setprio(1);
#pragma unroll
    for (int m = 0; m < 4; m++) {
#pragma unroll
      for (int n = 0; n < 4; n++) {
#pragma unroll
        for (int ks = 0; ks < 2; ks++) {
          accg[m][n] = __builtin_amdgcn_mfma_f32_16x16x32_bf16(af[m][ks], bg[n][ks], accg[m][n], 0, 0, 0);
          accu[m][n] = __builtin_amdgcn_mfma_f32_16x16x32_bf16(af[m][ks], bu[n][ks], accu[m][n], 0, 0, 0);
        }
      }
    }
    __builtin_amdgcn_s_setprio(0);
    __syncthreads();
    cur ^= 1;
  }
#pragma unroll
  for (int m = 0; m < 4; m++) {
    int rowl = m0 + wm * 64 + m * 16 + lk * 4;
#pragma unroll
    for (int n = 0; n < 4; n++) {
      int col = n0 + wn * 64 + n * 16 + lr;
#pragma unroll
      for (int j = 0; j < 4; j++) {
        float g = accg[m][n][j], u = accu[m][n][j];
        float s = g / (1.f + __expf(-g));
        unsigned short hv = f2bf(s * u);
        if (routed) {
          if (rowl + j < cnt) h_r[(size_t)(gbase + rowl + j) * DE + col] = hv;
        } else {
          h_s[(size_t)(rowl + j) * DS + (z - 8) * 1408 + col] = hv;
        }
      }
    }
  }
}

// ---------------- down: 256x256, 8-wave, 8-phase counted-vmcnt (R14 body) ----------------
__global__ __launch_bounds__(512, 1) void down_kernel(
    const ushort_t* __restrict__ h_r, const ushort_t* __restrict__ h_s,
    const int* __restrict__ counts, const int* __restrict__ ebase,
    const int* __restrict__ dn_off,
    const ushort_t* __restrict__ Wbd_e, const ushort_t* __restrict__ Wbd_s,
    float* __restrict__ oe, float* __restrict__ out) {
  extern __shared__ char smem[];   // 128KB: A[2buf][2half][16K] @0 | B[2buf][2half][16K] @64K

  int b = blockIdx.x;
  int c = (b & 7) * (DN_NB >> 3) + (b >> 3);
  int off[10];
#pragma unroll
  for (int zz = 0; zz < 10; zz++) off[zz] = dn_off[zz];
  if (c >= off[9]) return;
  int z = 0;
#pragma unroll
  for (int zz = 1; zz < 9; zz++) if (c >= off[zz]) z = zz;
  int cz = c - off[z];

  bool routed = (z < 8);
  int cnt, gbase, K, Lm;
  const ushort_t* Abase;
  const ushort_t* Bw;
  if (routed) {
    cnt = counts[z]; gbase = ebase[z];
    Lm = (cnt + 255) >> 8;
    K = DE;
    Abase = h_r + (size_t)gbase * DE;
    Bw = Wbd_e + (size_t)z * DH * DE;
  } else {
    cnt = T_TOK; gbase = 0; Lm = 8;
    K = DS;
    Abase = h_s;
    Bw = Wbd_s;
  }
  int mt = cz % Lm, y = cz / Lm;
  int m0 = mt * 256, n0 = y * 256;

  int tid = threadIdx.x;
  int lane = tid & 63, w = tid >> 6;
  int lr = lane & 15, lk = lane >> 4;
  int wm = w >> 2, wn = w & 3;

  const ushort_t* asrc[2][2];
  const ushort_t* bsrc[2][2];
  int sdst[2][2];
#pragma unroll
  for (int h = 0; h < 2; h++) {
#pragma unroll
    for (int j = 0; j < 2; j++) {
      int r = h * 128 + (w * 2 + j) * 8 + (lane >> 3);
      int cs = (lane & 7) ^ (r & 7);
      asrc[h][j] = Abase + (size_t)(m0 + r) * K + cs * 8;
      bsrc[h][j] = Bw + (size_t)(n0 + r) * K + cs * 8;
      sdst[h][j] = h * 16384 + (w * 2 + j) * 1024;
    }
  }

  f32x4 acc[8][4] = {};

#define DN_ST_A(p, h, k0)                                              \
  { char* _d = smem + (p) * 32768;                                     \
    gl_lds16(asrc[h][0] + (k0), _d + sdst[h][0]);                      \
    gl_lds16(asrc[h][1] + (k0), _d + sdst[h][1]); }
#define DN_ST_B(p, h, k0)                                              \
  { char* _d = smem + 65536 + (p) * 32768;                             \
    gl_lds16(bsrc[h][0] + (k0), _d + sdst[h][0]);                      \
    gl_lds16(bsrc[h][1] + (k0), _d + sdst[h][1]); }

  const int nt = K >> 6;
  DN_ST_A(0, 0, 0); DN_ST_A(0, 1, 0);
  DN_ST_B(0, 0, 0); DN_ST_B(0, 1, 0);
  DN_ST_B(1, 0, 64); DN_ST_B(1, 1, 64);
  asm volatile("s_waitcnt vmcnt(4)" ::: "memory");
  FENCE(); __builtin_amdgcn_s_barrier(); FENCE();

  short8 bfr[4][2];
  for (int t = 0; t < nt; t++) {
    int p = t & 1;
    const char* ab = smem + p * 32768;
    const char* bb = smem + 65536 + p * 32768;
    int k1 = (t + 1) * 64, k2 = (t + 2) * 64;
#pragma unroll
    for (int ph = 0; ph < 4; ph++) {
      if (ph == 0) {
#pragma unroll
        for (int n = 0; n < 4; n++) {
#pragma unroll
          for (int ks = 0; ks < 2; ks++) {
            int cc = wn * 64 + n * 16 + lr;
            bfr[n][ks] = *(const short8*)(bb + cc * 128 + ((ks * 64 + lk * 16) ^ ((cc & 7) << 4)));
          }
        }
      }
      short8 af[2][2];
#pragma unroll
      for (int m2 = 0; m2 < 2; m2++) {
#pragma unroll
        for (int ks = 0; ks < 2; ks++) {
          int rr = wm * 128 + ph * 32 + m2 * 16 + lr;
          af[m2][ks] = *(const short8*)(ab + rr * 128 + ((ks * 64 + lk * 16) ^ ((rr & 7) << 4)));
        }
      }
      if      (ph == 0) { if (t + 1 < nt) DN_ST_A(p ^ 1, 0, k1); }
      else if (ph == 1) { if (t + 1 < nt) DN_ST_A(p ^ 1, 1, k1); }
      else if (ph == 2) { if (t + 2 < nt) DN_ST_B(p, 0, k2); }
      else {
        if (t + 2 < nt) { DN_ST_B(p, 1, k2); asm volatile("s_waitcnt vmcnt(4)" ::: "memory"); }
        else            {                    asm volatile("s_waitcnt vmcnt(0)" ::: "memory"); }
      }
      FENCE(); __builtin_amdgcn_s_barrier(); FENCE();
      __builtin_amdgcn_s_setprio(1);
#pragma unroll
      for (int m2 = 0; m2 < 2; m2++) {
#pragma unroll
        for (int n = 0; n < 4; n++) {
#pragma unroll
          for (int ks = 0; ks < 2; ks++) {
            acc[ph * 2 + m2][n] = __builtin_amdgcn_mfma_f32_16x16x32_bf16(
                af[m2][ks], bfr[n][ks], acc[ph * 2 + m2][n], 0, 0, 0);
          }
        }
      }
      __builtin_amdgcn_s_setprio(0);
      FENCE(); __builtin_amdgcn_s_barrier(); FENCE();
    }
  }
#pragma unroll
  for (int m = 0; m < 8; m++) {
    int rowl = m0 + wm * 128 + m * 16 + lk * 4;
#pragma unroll
    for (int n = 0; n < 4; n++) {
      int col = n0 + wn * 64 + n * 16 + lr;
#pragma unroll
      for (int j = 0; j < 4; j++) {
        if (routed) {
          if (rowl + j < cnt) oe[(size_t)(gbase + rowl + j) * DH + col] = acc[m][n][j];
        } else {
          out[(size_t)(rowl + j) * DH + col] = acc[m][n][j];
        }
      }
    }
  }
}

// ---------------- combine ----------------
__global__ void combine_kernel(const int* __restrict__ tok_gslot,
                               const float* __restrict__ tok_w,
                               const float* __restrict__ oe,
                               float* __restrict__ out) {
  int t = blockIdx.x;
  int g1 = tok_gslot[2 * t], g2 = tok_gslot[2 * t + 1];
  float w1 = tok_w[2 * t], w2 = tok_w[2 * t + 1];
  int i = threadIdx.x * 8;
  const float4* p1 = (const float4*)(oe + (size_t)g1 * DH + i);
  const float4* p2 = (const float4*)(oe + (size_t)g2 * DH + i);
  float4* po = (float4*)(out + (size_t)t * DH + i);
  float4 a0 = p1[0], a1 = p1[1];
  float4 b0 = p2[0], b1 = p2[1];
  float4 o0 = po[0], o1 = po[1];
  o0.x += w1 * a0.x + w2 * b0.x;  o0.y += w1 * a0.y + w2 * b0.y;
  o0.z += w1 * a0.z + w2 * b0.z;  o0.w += w1 * a0.w + w2 * b0.w;
  o1.x += w1 * a1.x + w2 * b1.x;  o1.y += w1 * a1.y + w2 * b1.y;
  o1.z += w1 * a1.z + w2 * b1.z;  o1.w += w1 * a1.w + w2 * b1.w;
  po[0] = o0; po[1] = o1;
}

extern "C" void kernel_launch(void* const* d_in, const int* in_sizes, int n_in,
                              void* d_out, int out_size, void* d_ws, size_t ws_size,
                              hipStream_t stream) {
  const float* x    = (const float*)d_in[0];
  const float* gW   = (const float*)d_in[1];
  const float* Wg_e = (const float*)d_in[2];
  const float* Wu_e = (const float*)d_in[3];
  const float* Wd_e = (const float*)d_in[4];
  const float* Wg_s = (const float*)d_in[5];
  const float* Wu_s = (const float*)d_in[6];
  const float* Wd_s = (const float*)d_in[7];
  float* out = (float*)d_out;

  char* ws = (char*)d_ws;
  int*   counts   = (int*)ws;
  int*   ebase    = (int*)(ws + 64);
  int*   gu_off   = (int*)(ws + 128);
  int*   dn_off   = (int*)(ws + 192);
  int*   tok_e    = (int*)(ws + 256);
  int*   tok_slot = (int*)(ws + 256 + 16384);
  float* tok_w    = (float*)(ws + 256 + 32768);
  int*   slot2tok = (int*)(ws + 256 + 49152);
  ushort_t* xb  = (ushort_t*)(ws + 131072);
  ushort_t* h_r = (ushort_t*)(ws + 131072 + (size_t)T_TOK * DH * 2);
  ushort_t* h_s = h_r + (size_t)4096 * DE;
  float*    oe  = (float*)((char*)h_s + (size_t)T_TOK * DS * 2);
  ushort_t* wb  = (ushort_t*)((char*)oe + (size_t)4096 * DH * 4);
  ushort_t* wbg_e = wb;
  ushort_t* wbu_e = wb + NGEc;
  ushort_t* wbd_e = wb + 2 * NGEc;
  ushort_t* wbg_s = wb + 3 * NGEc;
  ushort_t* wbu_s = wbg_s + NGSc;
  ushort_t* wbd_s = wbg_s + 2 * NGSc;

  hipFuncSetAttribute((const void*)phaseB_kernel,
                      hipFuncAttributeMaxDynamicSharedMemorySize, 131072);
  hipFuncSetAttribute((const void*)down_kernel,
                      hipFuncAttributeMaxDynamicSharedMemorySize, 131072);

  hipMemsetAsync(counts, 0, 64, stream);
  phaseA_kernel<<<512 + PA_CVT_BLOCKS, 256, 0, stream>>>(
      x, gW, counts, tok_e, tok_slot, tok_w,
      Wg_e, Wu_e, Wg_s, Wu_s, wbg_e, wbu_e, wbg_s, wbu_s, xb);
  prefix_assign_kernel<<<1, 256, 0, stream>>>(counts, ebase, gu_off, dn_off,
                                              tok_e, tok_slot, slot2tok);
  phaseB_kernel<<<GU_NB + PB_CVT_BLOCKS, 512, 131072, stream>>>(
      xb, counts, ebase, gu_off, slot2tok, wbg_e, wbu_e, wbg_s, wbu_s, h_r, h_s,
      Wd_e, Wd_s, wbd_e, wbd_s);
  down_kernel<<<DN_NB, 512, 131072, stream>>>(
      h_r, h_s, counts, ebase, dn_off, wbd_e, wbd_s, oe, out);
  combine_kernel<<<T_TOK, 256, 0, stream>>>(tok_slot, tok_w, oe, out);
}

// Round 16
// 345.180 us; speedup vs baseline: 1.0251x; 1.0251x over previous
//
#include <hip/hip_runtime.h>

using short8 = __attribute__((ext_vector_type(8))) short;
using f32x4  = __attribute__((ext_vector_type(4))) float;
typedef unsigned short ushort_t;
typedef unsigned int u32;

#define T_TOK 2048
#define DH 2048
#define DE 1408
#define DS 2816
#define GU_NB 440   // gateup 256x128 tiles, multiple of 8
#define DN_NB 256   // down 256x256 tiles, multiple of 8

#define NGEc 23068672UL
#define NGSc 5767168UL
#define NXc  4194304UL
#define PA_CVT_BLOCKS 30208   // (2*NGE + 2*NGS + NX)/2048, one chunk per block
#define PB_CVT_BLOCKS 7040

#define FENCE() asm volatile("" ::: "memory")

__device__ __forceinline__ unsigned short f2bf(float f) {
  unsigned u = __float_as_uint(f);
  u += 0x7FFF + ((u >> 16) & 1);
  return (unsigned short)(u >> 16);
}

__device__ __forceinline__ void gl_lds16(const void* g, void* l) {
  __builtin_amdgcn_global_load_lds((const __attribute__((address_space(1))) u32*)g,
                                   (__attribute__((address_space(3))) u32*)l, 16, 0, 0);
}

__device__ __forceinline__ short8 pack_bf8(float4 a, float4 b) {
  short8 o;
  o[0] = (short)f2bf(a.x); o[1] = (short)f2bf(a.y);
  o[2] = (short)f2bf(a.z); o[3] = (short)f2bf(a.w);
  o[4] = (short)f2bf(b.x); o[5] = (short)f2bf(b.y);
  o[6] = (short)f2bf(b.z); o[7] = (short)f2bf(b.w);
  return o;
}

// ---------------- phase A: router (512 blocks) || cvt Wg_e,Wu_e,Wg_s,Wu_s,x (per-block chunk) ----------------
__global__ void phaseA_kernel(const float* __restrict__ x, const float* __restrict__ gW,
                              int* __restrict__ counts, int* __restrict__ tok_e,
                              int* __restrict__ tok_slot, float* __restrict__ tok_w,
                              const float* __restrict__ Wg_e, const float* __restrict__ Wu_e,
                              const float* __restrict__ Wg_s, const float* __restrict__ Wu_s,
                              ushort_t* wbg_e, ushort_t* wbu_e,
                              ushort_t* wbg_s, ushort_t* wbu_s, ushort_t* xb) {
  int b = blockIdx.x;
  int tid = threadIdx.x;
  if (b < 512) {
    int wid = tid >> 6, lane = tid & 63;
    int t = b * 4 + wid;
    float acc[8] = {0.f,0.f,0.f,0.f,0.f,0.f,0.f,0.f};
    const float* xt = x + (size_t)t * DH;
    for (int i = lane; i < DH; i += 64) {
      float xv = xt[i];
#pragma unroll
      for (int e = 0; e < 8; e++) acc[e] += xv * gW[e * DH + i];
    }
#pragma unroll
    for (int e = 0; e < 8; e++) {
#pragma unroll
      for (int off = 32; off > 0; off >>= 1) acc[e] += __shfl_xor(acc[e], off);
    }
    if (lane == 0) {
      float mx = acc[0];
      for (int e = 1; e < 8; e++) mx = fmaxf(mx, acc[e]);
      float p[8], se = 0.f;
      for (int e = 0; e < 8; e++) { p[e] = __expf(acc[e] - mx); se += p[e]; }
      for (int e = 0; e < 8; e++) p[e] /= se;
      int i1 = 0;
      for (int e = 1; e < 8; e++) if (p[e] > p[i1]) i1 = e;
      int i2 = (i1 == 0) ? 1 : 0;
      for (int e = 0; e < 8; e++) if (e != i1 && p[e] > p[i2]) i2 = e;
      int s1 = atomicAdd(&counts[i1], 1);
      int s2 = atomicAdd(&counts[i2], 1);
      tok_e[2 * t] = i1;     tok_e[2 * t + 1] = i2;
      tok_slot[2 * t] = s1;  tok_slot[2 * t + 1] = s2;
      tok_w[2 * t] = p[i1];  tok_w[2 * t + 1] = p[i2];
    }
    return;
  }
  size_t i = (size_t)(b - 512) * 2048 + (size_t)tid * 8;
  const float* s; ushort_t* d; size_t o;
  if      (i < NGEc)                    { s = Wg_e; d = wbg_e; o = i; }
  else if (i < 2 * NGEc)                { s = Wu_e; d = wbu_e; o = i - NGEc; }
  else if (i < 2 * NGEc + NGSc)         { s = Wg_s; d = wbg_s; o = i - 2 * NGEc; }
  else if (i < 2 * NGEc + 2 * NGSc)     { s = Wu_s; d = wbu_s; o = i - 2 * NGEc - NGSc; }
  else                                  { s = x;    d = xb;    o = i - 2 * NGEc - 2 * NGSc; }
  float4 a = *(const float4*)(s + o);
  float4 bb = *(const float4*)(s + o + 4);
  __builtin_nontemporal_store(pack_bf8(a, bb), (short8*)(d + o));
}

// ---------------- prefix ----------------
__global__ void prefix_assign_kernel(const int* __restrict__ counts, int* __restrict__ ebase,
                                     int* __restrict__ gu_off, int* __restrict__ dn_off,
                                     const int* __restrict__ tok_e, int* __restrict__ tok_slot,
                                     int* __restrict__ slot2tok) {
  __shared__ int sbase[8];
  if (threadIdx.x == 0) {
    int a = 0;
    for (int e = 0; e < 8; e++) { sbase[e] = a; ebase[e] = a; a += counts[e]; }
    int g = 0, d = 0;
    for (int z = 0; z < 8; z++) {
      gu_off[z] = g; dn_off[z] = d;
      int Lg = (counts[z] + 255) >> 8;
      g += Lg * 11;
      int Ld = (counts[z] + 255) >> 8;
      d += Ld * 8;
    }
    gu_off[8] = g; g += 88;
    gu_off[9] = g; g += 88;
    gu_off[10] = g;
    dn_off[8] = d; d += 64;
    dn_off[9] = d;
  }
  __syncthreads();
  for (int idx = threadIdx.x; idx < T_TOK * 2; idx += blockDim.x) {
    int e = tok_e[idx];
    int g = sbase[e] + tok_slot[idx];
    tok_slot[idx] = g;
    slot2tok[g] = idx >> 1;
  }
}

// ---------------- phase B: gateup 256x128 8-wave 2-phase || cvt Wd ----------------
__global__ __launch_bounds__(512, 1) void phaseB_kernel(
    const ushort_t* __restrict__ xb, const int* __restrict__ counts,
    const int* __restrict__ ebase, const int* __restrict__ gu_off,
    const int* __restrict__ slot2tok,
    const ushort_t* __restrict__ Wbg_e, const ushort_t* __restrict__ Wbu_e,
    const ushort_t* __restrict__ Wbg_s, const ushort_t* __restrict__ Wbu_s,
    ushort_t* __restrict__ h_r, ushort_t* __restrict__ h_s,
    const float* __restrict__ Wd_e, const float* __restrict__ Wd_s,
    ushort_t* wbd_e, ushort_t* wbd_s) {
  extern __shared__ char smem[];   // 128KB: A[2][32K] @0 | Bg[2][16K] @64K | Bu[2][16K] @96K
  int tid = threadIdx.x;
  if (blockIdx.x >= GU_NB) {
    size_t i = (size_t)(blockIdx.x - GU_NB) * 4096 + (size_t)tid * 8;
    const float* s; ushort_t* d; size_t o;
    if (i < NGEc) { s = Wd_e; d = wbd_e; o = i; }
    else          { s = Wd_s; d = wbd_s; o = i - NGEc; }
    float4 a = *(const float4*)(s + o);
    float4 bb = *(const float4*)(s + o + 4);
    __builtin_nontemporal_store(pack_bf8(a, bb), (short8*)(d + o));
    return;
  }
  int b = blockIdx.x;
  int c = (b & 7) * (GU_NB >> 3) + (b >> 3);
  int off[11];
#pragma unroll
  for (int zz = 0; zz < 11; zz++) off[zz] = gu_off[zz];
  if (c >= off[10]) return;
  int z = 0;
#pragma unroll
  for (int zz = 1; zz < 10; zz++) if (c >= off[zz]) z = zz;
  int cz = c - off[z];

  bool routed = (z < 8);
  int cnt, gbase, Lm;
  const ushort_t *Bg, *Bu;
  if (routed) {
    cnt = counts[z]; gbase = ebase[z];
    Lm = (cnt + 255) >> 8;
    Bg = Wbg_e + (size_t)z * DE * DH;
    Bu = Wbu_e + (size_t)z * DE * DH;
  } else {
    cnt = T_TOK; gbase = 0; Lm = 8;
    Bg = Wbg_s + (size_t)(z - 8) * 1408 * DH;
    Bu = Wbu_s + (size_t)(z - 8) * 1408 * DH;
  }
  int mt = cz % Lm, y = cz / Lm;
  int m0 = mt * 256, n0 = y * 128;

  int lane = tid & 63, w = tid >> 6;
  int lr = lane & 15, lk = lane >> 4;
  int wm = w >> 1, wn = w & 1;

  const ushort_t* asrc[4];
  int adst[4];
#pragma unroll
  for (int j = 0; j < 4; j++) {
    int r = (w * 4 + j) * 8 + (lane >> 3);
    int lrow = m0 + r;
    int tok = routed ? ((lrow < cnt) ? slot2tok[gbase + lrow] : 0) : lrow;
    int cs = (lane & 7) ^ (r & 7);
    asrc[j] = xb + (size_t)tok * DH + cs * 8;
    adst[j] = (w * 4 + j) * 1024;
  }
  const ushort_t* gsrc[2];
  const ushort_t* usrc[2];
  int wdst[2];
#pragma unroll
  for (int j = 0; j < 2; j++) {
    int r = (w * 2 + j) * 8 + (lane >> 3);
    int cs = (lane & 7) ^ (r & 7);
    gsrc[j] = Bg + (size_t)(n0 + r) * DH + cs * 8;
    usrc[j] = Bu + (size_t)(n0 + r) * DH + cs * 8;
    wdst[j] = (w * 2 + j) * 1024;
  }

  f32x4 accg[4][4] = {};
  f32x4 accu[4][4] = {};

#define GU_STAGE(buf, k0)                                             \
  {                                                                   \
    char* ab = smem + (buf) * 32768;                                  \
    char* gb = smem + 65536 + (buf) * 16384;                          \
    char* ub = smem + 98304 + (buf) * 16384;                          \
    _Pragma("unroll")                                                 \
    for (int j = 0; j < 4; j++) gl_lds16(asrc[j] + (k0), ab + adst[j]); \
    _Pragma("unroll")                                                 \
    for (int j = 0; j < 2; j++) {                                     \
      gl_lds16(gsrc[j] + (k0), gb + wdst[j]);                         \
      gl_lds16(usrc[j] + (k0), ub + wdst[j]);                         \
    }                                                                 \
  }

  const int nt = DH >> 6;   // 32
  GU_STAGE(0, 0);
  __syncthreads();
  int cur = 0;
  for (int t = 0; t < nt; t++) {
    if (t + 1 < nt) GU_STAGE(cur ^ 1, (t + 1) * 64);
    const char* ab = smem + cur * 32768;
    const char* gb = smem + 65536 + cur * 16384;
    const char* ub = smem + 98304 + cur * 16384;
    short8 af[4][2], bg[4][2], bu[4][2];
#pragma unroll
    for (int m = 0; m < 4; m++) {
#pragma unroll
      for (int ks = 0; ks < 2; ks++) {
        int rr = wm * 64 + m * 16 + lr;
        af[m][ks] = *(const short8*)(ab + rr * 128 + ((ks * 64 + lk * 16) ^ ((rr & 7) << 4)));
      }
    }
#pragma unroll
    for (int n = 0; n < 4; n++) {
#pragma unroll
      for (int ks = 0; ks < 2; ks++) {
        int cc = wn * 64 + n * 16 + lr;
        bg[n][ks] = *(const short8*)(gb + cc * 128 + ((ks * 64 + lk * 16) ^ ((cc & 7) << 4)));
        bu[n][ks] = *(const short8*)(ub + cc * 128 + ((ks * 64 + lk * 16) ^ ((cc & 7) << 4)));
      }
    }
    __builtin_amdgcn_s_setprio(1);
#pragma unroll
    for (int m = 0; m < 4; m++) {
#pragma unroll
      for (int n = 0; n < 4; n++) {
#pragma unroll
        for (int ks = 0; ks < 2; ks++) {
          accg[m][n] = __builtin_amdgcn_mfma_f32_16x16x32_bf16(af[m][ks], bg[n][ks], accg[m][n], 0, 0, 0);
          accu[m][n] = __builtin_amdgcn_mfma_f32_16x16x32_bf16(af[m][ks], bu[n][ks], accu[m][n], 0, 0, 0);
        }
      }
    }
    __builtin_amdgcn_s_setprio(0);
    __syncthreads();
    cur ^= 1;
  }
#pragma unroll
  for (int m = 0; m < 4; m++) {
    int rowl = m0 + wm * 64 + m * 16 + lk * 4;
#pragma unroll
    for (int n = 0; n < 4; n++) {
      int col = n0 + wn * 64 + n * 16 + lr;
#pragma unroll
      for (int j = 0; j < 4; j++) {
        float g = accg[m][n][j], u = accu[m][n][j];
        float s = g / (1.f + __expf(-g));
        unsigned short hv = f2bf(s * u);
        if (routed) {
          if (rowl + j < cnt) h_r[(size_t)(gbase + rowl + j) * DE + col] = hv;
        } else {
          h_s[(size_t)(rowl + j) * DS + (z - 8) * 1408 + col] = hv;
        }
      }
    }
  }
}

// ---------------- down: 256x256, 8-wave, 8-phase counted-vmcnt ----------------
__global__ __launch_bounds__(512, 1) void down_kernel(
    const ushort_t* __restrict__ h_r, const ushort_t* __restrict__ h_s,
    const int* __restrict__ counts, const int* __restrict__ ebase,
    const int* __restrict__ dn_off,
    const ushort_t* __restrict__ Wbd_e, const ushort_t* __restrict__ Wbd_s,
    float* __restrict__ oe, float* __restrict__ out) {
  extern __shared__ char smem[];   // 128KB: A[2buf][2half][16K] @0 | B[2buf][2half][16K] @64K

  int b = blockIdx.x;
  int c = (b & 7) * (DN_NB >> 3) + (b >> 3);
  int off[10];
#pragma unroll
  for (int zz = 0; zz < 10; zz++) off[zz] = dn_off[zz];
  if (c >= off[9]) return;
  int z = 0;
#pragma unroll
  for (int zz = 1; zz < 9; zz++) if (c >= off[zz]) z = zz;
  int cz = c - off[z];

  bool routed = (z < 8);
  int cnt, gbase, K, Lm;
  const ushort_t* Abase;
  const ushort_t* Bw;
  if (routed) {
    cnt = counts[z]; gbase = ebase[z];
    Lm = (cnt + 255) >> 8;
    K = DE;
    Abase = h_r + (size_t)gbase * DE;
    Bw = Wbd_e + (size_t)z * DH * DE;
  } else {
    cnt = T_TOK; gbase = 0; Lm = 8;
    K = DS;
    Abase = h_s;
    Bw = Wbd_s;
  }
  int mt = cz % Lm, y = cz / Lm;
  int m0 = mt * 256, n0 = y * 256;

  int tid = threadIdx.x;
  int lane = tid & 63, w = tid >> 6;
  int lr = lane & 15, lk = lane >> 4;
  int wm = w >> 2, wn = w & 3;

  const ushort_t* asrc[2][2];
  const ushort_t* bsrc[2][2];
  int sdst[2][2];
#pragma unroll
  for (int h = 0; h < 2; h++) {
#pragma unroll
    for (int j = 0; j < 2; j++) {
      int r = h * 128 + (w * 2 + j) * 8 + (lane >> 3);
      int cs = (lane & 7) ^ (r & 7);
      asrc[h][j] = Abase + (size_t)(m0 + r) * K + cs * 8;
      bsrc[h][j] = Bw + (size_t)(n0 + r) * K + cs * 8;
      sdst[h][j] = h * 16384 + (w * 2 + j) * 1024;
    }
  }

  f32x4 acc[8][4] = {};

#define DN_ST_A(p, h, k0)                                              \
  { char* _d = smem + (p) * 32768;                                     \
    gl_lds16(asrc[h][0] + (k0), _d + sdst[h][0]);                      \
    gl_lds16(asrc[h][1] + (k0), _d + sdst[h][1]); }
#define DN_ST_B(p, h, k0)                                              \
  { char* _d = smem + 65536 + (p) * 32768;                             \
    gl_lds16(bsrc[h][0] + (k0), _d + sdst[h][0]);                      \
    gl_lds16(bsrc[h][1] + (k0), _d + sdst[h][1]); }

  const int nt = K >> 6;
  DN_ST_A(0, 0, 0); DN_ST_A(0, 1, 0);
  DN_ST_B(0, 0, 0); DN_ST_B(0, 1, 0);
  DN_ST_B(1, 0, 64); DN_ST_B(1, 1, 64);
  asm volatile("s_waitcnt vmcnt(4)" ::: "memory");
  FENCE(); __builtin_amdgcn_s_barrier(); FENCE();

  short8 bfr[4][2];
  for (int t = 0; t < nt; t++) {
    int p = t & 1;
    const char* ab = smem + p * 32768;
    const char* bb = smem + 65536 + p * 32768;
    int k1 = (t + 1) * 64, k2 = (t + 2) * 64;
#pragma unroll
    for (int ph = 0; ph < 4; ph++) {
      if (ph == 0) {
#pragma unroll
        for (int n = 0; n < 4; n++) {
#pragma unroll
          for (int ks = 0; ks < 2; ks++) {
            int cc = wn * 64 + n * 16 + lr;
            bfr[n][ks] = *(const short8*)(bb + cc * 128 + ((ks * 64 + lk * 16) ^ ((cc & 7) << 4)));
          }
        }
      }
      short8 af[2][2];
#pragma unroll
      for (int m2 = 0; m2 < 2; m2++) {
#pragma unroll
        for (int ks = 0; ks < 2; ks++) {
          int rr = wm * 128 + ph * 32 + m2 * 16 + lr;
          af[m2][ks] = *(const short8*)(ab + rr * 128 + ((ks * 64 + lk * 16) ^ ((rr & 7) << 4)));
        }
      }
      if      (ph == 0) { if (t + 1 < nt) DN_ST_A(p ^ 1, 0, k1); }
      else if (ph == 1) { if (t + 1 < nt) DN_ST_A(p ^ 1, 1, k1); }
      else if (ph == 2) { if (t + 2 < nt) DN_ST_B(p, 0, k2); }
      else {
        if (t + 2 < nt) { DN_ST_B(p, 1, k2); asm volatile("s_waitcnt vmcnt(4)" ::: "memory"); }
        else            {                    asm volatile("s_waitcnt vmcnt(0)" ::: "memory"); }
      }
      FENCE(); __builtin_amdgcn_s_barrier(); FENCE();
      __builtin_amdgcn_s_setprio(1);
#pragma unroll
      for (int m2 = 0; m2 < 2; m2++) {
#pragma unroll
        for (int n = 0; n < 4; n++) {
#pragma unroll
          for (int ks = 0; ks < 2; ks++) {
            acc[ph * 2 + m2][n] = __builtin_amdgcn_mfma_f32_16x16x32_bf16(
                af[m2][ks], bfr[n][ks], acc[ph * 2 + m2][n], 0, 0, 0);
          }
        }
      }
      __builtin_amdgcn_s_setprio(0);
      FENCE(); __builtin_amdgcn_s_barrier(); FENCE();
    }
  }
#pragma unroll
  for (int m = 0; m < 8; m++) {
    int rowl = m0 + wm * 128 + m * 16 + lk * 4;
#pragma unroll
    for (int n = 0; n < 4; n++) {
      int col = n0 + wn * 64 + n * 16 + lr;
#pragma unroll
      for (int j = 0; j < 4; j++) {
        if (routed) {
          if (rowl + j < cnt) oe[(size_t)(gbase + rowl + j) * DH + col] = acc[m][n][j];
        } else {
          out[(size_t)(rowl + j) * DH + col] = acc[m][n][j];
        }
      }
    }
  }
}

// ---------------- combine ----------------
__global__ void combine_kernel(const int* __restrict__ tok_gslot,
                               const float* __restrict__ tok_w,
                               const float* __restrict__ oe,
                               float* __restrict__ out) {
  int t = blockIdx.x;
  int g1 = tok_gslot[2 * t], g2 = tok_gslot[2 * t + 1];
  float w1 = tok_w[2 * t], w2 = tok_w[2 * t + 1];
  int i = threadIdx.x * 8;
  const float4* p1 = (const float4*)(oe + (size_t)g1 * DH + i);
  const float4* p2 = (const float4*)(oe + (size_t)g2 * DH + i);
  float4* po = (float4*)(out + (size_t)t * DH + i);
  float4 a0 = p1[0], a1 = p1[1];
  float4 b0 = p2[0], b1 = p2[1];
  float4 o0 = po[0], o1 = po[1];
  o0.x += w1 * a0.x + w2 * b0.x;  o0.y += w1 * a0.y + w2 * b0.y;
  o0.z += w1 * a0.z + w2 * b0.z;  o0.w += w1 * a0.w + w2 * b0.w;
  o1.x += w1 * a1.x + w2 * b1.x;  o1.y += w1 * a1.y + w2 * b1.y;
  o1.z += w1 * a1.z + w2 * b1.z;  o1.w += w1 * a1.w + w2 * b1.w;
  po[0] = o0; po[1] = o1;
}

extern "C" void kernel_launch(void* const* d_in, const int* in_sizes, int n_in,
                              void* d_out, int out_size, void* d_ws, size_t ws_size,
                              hipStream_t stream) {
  const float* x    = (const float*)d_in[0];
  const float* gW   = (const float*)d_in[1];
  const float* Wg_e = (const float*)d_in[2];
  const float* Wu_e = (const float*)d_in[3];
  const float* Wd_e = (const float*)d_in[4];
  const float* Wg_s = (const float*)d_in[5];
  const float* Wu_s = (const float*)d_in[6];
  const float* Wd_s = (const float*)d_in[7];
  float* out = (float*)d_out;

  char* ws = (char*)d_ws;
  int*   counts   = (int*)ws;
  int*   ebase    = (int*)(ws + 64);
  int*   gu_off   = (int*)(ws + 128);
  int*   dn_off   = (int*)(ws + 192);
  int*   tok_e    = (int*)(ws + 256);
  int*   tok_slot = (int*)(ws + 256 + 16384);
  float* tok_w    = (float*)(ws + 256 + 32768);
  int*   slot2tok = (int*)(ws + 256 + 49152);
  ushort_t* xb  = (ushort_t*)(ws + 131072);
  ushort_t* h_r = (ushort_t*)(ws + 131072 + (size_t)T_TOK * DH * 2);
  ushort_t* h_s = h_r + (size_t)4096 * DE;
  float*    oe  = (float*)((char*)h_s + (size_t)T_TOK * DS * 2);
  ushort_t* wb  = (ushort_t*)((char*)oe + (size_t)4096 * DH * 4);
  ushort_t* wbg_e = wb;
  ushort_t* wbu_e = wb + NGEc;
  ushort_t* wbd_e = wb + 2 * NGEc;
  ushort_t* wbg_s = wb + 3 * NGEc;
  ushort_t* wbu_s = wbg_s + NGSc;
  ushort_t* wbd_s = wbg_s + 2 * NGSc;

  hipFuncSetAttribute((const void*)phaseB_kernel,
                      hipFuncAttributeMaxDynamicSharedMemorySize, 131072);
  hipFuncSetAttribute((const void*)down_kernel,
                      hipFuncAttributeMaxDynamicSharedMemorySize, 131072);

  hipMemsetAsync(counts, 0, 64, stream);
  phaseA_kernel<<<512 + PA_CVT_BLOCKS, 256, 0, stream>>>(
      x, gW, counts, tok_e, tok_slot, tok_w,
      Wg_e, Wu_e, Wg_s, Wu_s, wbg_e, wbu_e, wbg_s, wbu_s, xb);
  prefix_assign_kernel<<<1, 256, 0, stream>>>(counts, ebase, gu_off, dn_off,
                                              tok_e, tok_slot, slot2tok);
  phaseB_kernel<<<GU_NB + PB_CVT_BLOCKS, 512, 131072, stream>>>(
      xb, counts, ebase, gu_off, slot2tok, wbg_e, wbu_e, wbg_s, wbu_s, h_r, h_s,
      Wd_e, Wd_s, wbd_e, wbd_s);
  down_kernel<<<DN_NB, 512, 131072, stream>>>(
      h_r, h_s, counts, ebase, dn_off, wbd_e, wbd_s, oe, out);
  combine_kernel<<<T_TOK, 256, 0, stream>>>(tok_slot, tok_w, oe, out);
}

// Round 17
// 338.900 us; speedup vs baseline: 1.0441x; 1.0185x over previous
//
#include <hip/hip_runtime.h>

using short8 = __attribute__((ext_vector_type(8))) short;
using f32x4  = __attribute__((ext_vector_type(4))) float;
typedef unsigned short ushort_t;
typedef unsigned int u32;

#define T_TOK 2048
#define DH 2048
#define DE 1408
#define DS 2816
#define GU_NB 440   // gateup 256x128 tiles, multiple of 8
#define DN_NB 256   // down 256x256 tiles, multiple of 8

#define NGEc 23068672UL
#define NGSc 5767168UL
#define NXc  4194304UL
#define PA_CVT_BLOCKS 30208   // (2*NGE + 2*NGS + NX)/2048, one chunk per block
#define PB_CVT_BLOCKS 7040

#define FENCE() asm volatile("" ::: "memory")

__device__ __forceinline__ unsigned short f2bf(float f) {
  unsigned u = __float_as_uint(f);
  u += 0x7FFF + ((u >> 16) & 1);
  return (unsigned short)(u >> 16);
}

__device__ __forceinline__ void gl_lds16(const void* g, void* l) {
  __builtin_amdgcn_global_load_lds((const __attribute__((address_space(1))) u32*)g,
                                   (__attribute__((address_space(3))) u32*)l, 16, 0, 0);
}

__device__ __forceinline__ short8 pack_bf8(float4 a, float4 b) {
  short8 o;
  o[0] = (short)f2bf(a.x); o[1] = (short)f2bf(a.y);
  o[2] = (short)f2bf(a.z); o[3] = (short)f2bf(a.w);
  o[4] = (short)f2bf(b.x); o[5] = (short)f2bf(b.y);
  o[6] = (short)f2bf(b.z); o[7] = (short)f2bf(b.w);
  return o;
}

// ---------------- phase A: router (512 blocks) || cvt Wg_e,Wu_e,Wg_s,Wu_s,x ----------------
__global__ void phaseA_kernel(const float* __restrict__ x, const float* __restrict__ gW,
                              int* __restrict__ counts, int* __restrict__ tok_e,
                              int* __restrict__ tok_slot, float* __restrict__ tok_w,
                              const float* __restrict__ Wg_e, const float* __restrict__ Wu_e,
                              const float* __restrict__ Wg_s, const float* __restrict__ Wu_s,
                              ushort_t* wbg_e, ushort_t* wbu_e,
                              ushort_t* wbg_s, ushort_t* wbu_s, ushort_t* xb) {
  int b = blockIdx.x;
  int tid = threadIdx.x;
  if (b < 512) {
    int wid = tid >> 6, lane = tid & 63;
    int t = b * 4 + wid;
    float acc[8] = {0.f,0.f,0.f,0.f,0.f,0.f,0.f,0.f};
    const float* xt = x + (size_t)t * DH;
    for (int i = lane; i < DH; i += 64) {
      float xv = xt[i];
#pragma unroll
      for (int e = 0; e < 8; e++) acc[e] += xv * gW[e * DH + i];
    }
#pragma unroll
    for (int e = 0; e < 8; e++) {
#pragma unroll
      for (int off = 32; off > 0; off >>= 1) acc[e] += __shfl_xor(acc[e], off);
    }
    if (lane == 0) {
      float mx = acc[0];
      for (int e = 1; e < 8; e++) mx = fmaxf(mx, acc[e]);
      float p[8], se = 0.f;
      for (int e = 0; e < 8; e++) { p[e] = __expf(acc[e] - mx); se += p[e]; }
      for (int e = 0; e < 8; e++) p[e] /= se;
      int i1 = 0;
      for (int e = 1; e < 8; e++) if (p[e] > p[i1]) i1 = e;
      int i2 = (i1 == 0) ? 1 : 0;
      for (int e = 0; e < 8; e++) if (e != i1 && p[e] > p[i2]) i2 = e;
      int s1 = atomicAdd(&counts[i1], 1);
      int s2 = atomicAdd(&counts[i2], 1);
      tok_e[2 * t] = i1;     tok_e[2 * t + 1] = i2;
      tok_slot[2 * t] = s1;  tok_slot[2 * t + 1] = s2;
      tok_w[2 * t] = p[i1];  tok_w[2 * t + 1] = p[i2];
    }
    return;
  }
  size_t i = (size_t)(b - 512) * 2048 + (size_t)tid * 8;
  const float* s; ushort_t* d; size_t o;
  if      (i < NGEc)                    { s = Wg_e; d = wbg_e; o = i; }
  else if (i < 2 * NGEc)                { s = Wu_e; d = wbu_e; o = i - NGEc; }
  else if (i < 2 * NGEc + NGSc)         { s = Wg_s; d = wbg_s; o = i - 2 * NGEc; }
  else if (i < 2 * NGEc + 2 * NGSc)     { s = Wu_s; d = wbu_s; o = i - 2 * NGEc - NGSc; }
  else                                  { s = x;    d = xb;    o = i - 2 * NGEc - 2 * NGSc; }
  float4 a = *(const float4*)(s + o);
  float4 bb = *(const float4*)(s + o + 4);
  *(short8*)(d + o) = pack_bf8(a, bb);   // plain store (nontemporal cost ~14us on this stream)
}

// ---------------- prefix ----------------
__global__ void prefix_assign_kernel(const int* __restrict__ counts, int* __restrict__ ebase,
                                     int* __restrict__ gu_off, int* __restrict__ dn_off,
                                     const int* __restrict__ tok_e, int* __restrict__ tok_slot,
                                     int* __restrict__ slot2tok) {
  __shared__ int sbase[8];
  if (threadIdx.x == 0) {
    int a = 0;
    for (int e = 0; e < 8; e++) { sbase[e] = a; ebase[e] = a; a += counts[e]; }
    int g = 0, d = 0;
    for (int z = 0; z < 8; z++) {
      gu_off[z] = g; dn_off[z] = d;
      int Lg = (counts[z] + 255) >> 8;
      g += Lg * 11;
      int Ld = (counts[z] + 255) >> 8;
      d += Ld * 8;
    }
    gu_off[8] = g; g += 88;
    gu_off[9] = g; g += 88;
    gu_off[10] = g;
    dn_off[8] = d; d += 64;
    dn_off[9] = d;
  }
  __syncthreads();
  for (int idx = threadIdx.x; idx < T_TOK * 2; idx += blockDim.x) {
    int e = tok_e[idx];
    int g = sbase[e] + tok_slot[idx];
    tok_slot[idx] = g;
    slot2tok[g] = idx >> 1;
  }
}

// ---------------- phase B: gateup 256x128 8-wave 2-phase || cvt Wd ----------------
__global__ __launch_bounds__(512, 1) void phaseB_kernel(
    const ushort_t* __restrict__ xb, const int* __restrict__ counts,
    const int* __restrict__ ebase, const int* __restrict__ gu_off,
    const int* __restrict__ slot2tok,
    const ushort_t* __restrict__ Wbg_e, const ushort_t* __restrict__ Wbu_e,
    const ushort_t* __restrict__ Wbg_s, const ushort_t* __restrict__ Wbu_s,
    ushort_t* __restrict__ h_r, ushort_t* __restrict__ h_s,
    const float* __restrict__ Wd_e, const float* __restrict__ Wd_s,
    ushort_t* wbd_e, ushort_t* wbd_s) {
  extern __shared__ char smem[];   // 128KB: A[2][32K] @0 | Bg[2][16K] @64K | Bu[2][16K] @96K
  int tid = threadIdx.x;
  if (blockIdx.x >= GU_NB) {
    size_t i = (size_t)(blockIdx.x - GU_NB) * 4096 + (size_t)tid * 8;
    const float* s; ushort_t* d; size_t o;
    if (i < NGEc) { s = Wd_e; d = wbd_e; o = i; }
    else          { s = Wd_s; d = wbd_s; o = i - NGEc; }
    float4 a = *(const float4*)(s + o);
    float4 bb = *(const float4*)(s + o + 4);
    *(short8*)(d + o) = pack_bf8(a, bb);
    return;
  }
  int b = blockIdx.x;
  int c = (b & 7) * (GU_NB >> 3) + (b >> 3);
  int off[11];
#pragma unroll
  for (int zz = 0; zz < 11; zz++) off[zz] = gu_off[zz];
  if (c >= off[10]) return;
  int z = 0;
#pragma unroll
  for (int zz = 1; zz < 10; zz++) if (c >= off[zz]) z = zz;
  int cz = c - off[z];

  bool routed = (z < 8);
  int cnt, gbase, Lm;
  const ushort_t *Bg, *Bu;
  if (routed) {
    cnt = counts[z]; gbase = ebase[z];
    Lm = (cnt + 255) >> 8;
    Bg = Wbg_e + (size_t)z * DE * DH;
    Bu = Wbu_e + (size_t)z * DE * DH;
  } else {
    cnt = T_TOK; gbase = 0; Lm = 8;
    Bg = Wbg_s + (size_t)(z - 8) * 1408 * DH;
    Bu = Wbu_s + (size_t)(z - 8) * 1408 * DH;
  }
  int mt = cz % Lm, y = cz / Lm;
  int m0 = mt * 256, n0 = y * 128;

  int lane = tid & 63, w = tid >> 6;
  int lr = lane & 15, lk = lane >> 4;
  int wm = w >> 1, wn = w & 1;

  const ushort_t* asrc[4];
  int adst[4];
#pragma unroll
  for (int j = 0; j < 4; j++) {
    int r = (w * 4 + j) * 8 + (lane >> 3);
    int lrow = m0 + r;
    int tok = routed ? ((lrow < cnt) ? slot2tok[gbase + lrow] : 0) : lrow;
    int cs = (lane & 7) ^ (r & 7);
    asrc[j] = xb + (size_t)tok * DH + cs * 8;
    adst[j] = (w * 4 + j) * 1024;
  }
  const ushort_t* gsrc[2];
  const ushort_t* usrc[2];
  int wdst[2];
#pragma unroll
  for (int j = 0; j < 2; j++) {
    int r = (w * 2 + j) * 8 + (lane >> 3);
    int cs = (lane & 7) ^ (r & 7);
    gsrc[j] = Bg + (size_t)(n0 + r) * DH + cs * 8;
    usrc[j] = Bu + (size_t)(n0 + r) * DH + cs * 8;
    wdst[j] = (w * 2 + j) * 1024;
  }

  f32x4 accg[4][4] = {};
  f32x4 accu[4][4] = {};

#define GU_STAGE(buf, k0)                                             \
  {                                                                   \
    char* ab = smem + (buf) * 32768;                                  \
    char* gb = smem + 65536 + (buf) * 16384;                          \
    char* ub = smem + 98304 + (buf) * 16384;                          \
    _Pragma("unroll")                                                 \
    for (int j = 0; j < 4; j++) gl_lds16(asrc[j] + (k0), ab + adst[j]); \
    _Pragma("unroll")                                                 \
    for (int j = 0; j < 2; j++) {                                     \
      gl_lds16(gsrc[j] + (k0), gb + wdst[j]);                         \
      gl_lds16(usrc[j] + (k0), ub + wdst[j]);                         \
    }                                                                 \
  }

  const int nt = DH >> 6;   // 32
  GU_STAGE(0, 0);
  __syncthreads();
  int cur = 0;
  for (int t = 0; t < nt; t++) {
    if (t + 1 < nt) GU_STAGE(cur ^ 1, (t + 1) * 64);
    const char* ab = smem + cur * 32768;
    const char* gb = smem + 65536 + cur * 16384;
    const char* ub = smem + 98304 + cur * 16384;
    short8 af[4][2], bg[4][2], bu[4][2];
#pragma unroll
    for (int m = 0; m < 4; m++) {
#pragma unroll
      for (int ks = 0; ks < 2; ks++) {
        int rr = wm * 64 + m * 16 + lr;
        af[m][ks] = *(const short8*)(ab + rr * 128 + ((ks * 64 + lk * 16) ^ ((rr & 7) << 4)));
      }
    }
#pragma unroll
    for (int n = 0; n < 4; n++) {
#pragma unroll
      for (int ks = 0; ks < 2; ks++) {
        int cc = wn * 64 + n * 16 + lr;
        bg[n][ks] = *(const short8*)(gb + cc * 128 + ((ks * 64 + lk * 16) ^ ((cc & 7) << 4)));
        bu[n][ks] = *(const short8*)(ub + cc * 128 + ((ks * 64 + lk * 16) ^ ((cc & 7) << 4)));
      }
    }
    __builtin_amdgcn_s_setprio(1);
#pragma unroll
    for (int m = 0; m < 4; m++) {
#pragma unroll
      for (int n = 0; n < 4; n++) {
#pragma unroll
        for (int ks = 0; ks < 2; ks++) {
          accg[m][n] = __builtin_amdgcn_mfma_f32_16x16x32_bf16(af[m][ks], bg[n][ks], accg[m][n], 0, 0, 0);
          accu[m][n] = __builtin_amdgcn_mfma_f32_16x16x32_bf16(af[m][ks], bu[n][ks], accu[m][n], 0, 0, 0);
        }
      }
    }
    __builtin_amdgcn_s_setprio(0);
    __syncthreads();
    cur ^= 1;
  }
#pragma unroll
  for (int m = 0; m < 4; m++) {
    int rowl = m0 + wm * 64 + m * 16 + lk * 4;
#pragma unroll
    for (int n = 0; n < 4; n++) {
      int col = n0 + wn * 64 + n * 16 + lr;
#pragma unroll
      for (int j = 0; j < 4; j++) {
        float g = accg[m][n][j], u = accu[m][n][j];
        float s = g / (1.f + __expf(-g));
        unsigned short hv = f2bf(s * u);
        if (routed) {
          if (rowl + j < cnt) h_r[(size_t)(gbase + rowl + j) * DE + col] = hv;
        } else {
          h_s[(size_t)(rowl + j) * DS + (z - 8) * 1408 + col] = hv;
        }
      }
    }
  }
}

// ---------------- down: 256x256, 8-wave, 8-phase counted-vmcnt ----------------
__global__ __launch_bounds__(512, 1) void down_kernel(
    const ushort_t* __restrict__ h_r, const ushort_t* __restrict__ h_s,
    const int* __restrict__ counts, const int* __restrict__ ebase,
    const int* __restrict__ dn_off,
    const ushort_t* __restrict__ Wbd_e, const ushort_t* __restrict__ Wbd_s,
    float* __restrict__ oe, float* __restrict__ out) {
  extern __shared__ char smem[];   // 128KB: A[2buf][2half][16K] @0 | B[2buf][2half][16K] @64K

  int b = blockIdx.x;
  int c = (b & 7) * (DN_NB >> 3) + (b >> 3);
  int off[10];
#pragma unroll
  for (int zz = 0; zz < 10; zz++) off[zz] = dn_off[zz];
  if (c >= off[9]) return;
  int z = 0;
#pragma unroll
  for (int zz = 1; zz < 9; zz++) if (c >= off[zz]) z = zz;
  int cz = c - off[z];

  bool routed = (z < 8);
  int cnt, gbase, K, Lm;
  const ushort_t* Abase;
  const ushort_t* Bw;
  if (routed) {
    cnt = counts[z]; gbase = ebase[z];
    Lm = (cnt + 255) >> 8;
    K = DE;
    Abase = h_r + (size_t)gbase * DE;
    Bw = Wbd_e + (size_t)z * DH * DE;
  } else {
    cnt = T_TOK; gbase = 0; Lm = 8;
    K = DS;
    Abase = h_s;
    Bw = Wbd_s;
  }
  int mt = cz % Lm, y = cz / Lm;
  int m0 = mt * 256, n0 = y * 256;

  int tid = threadIdx.x;
  int lane = tid & 63, w = tid >> 6;
  int lr = lane & 15, lk = lane >> 4;
  int wm = w >> 2, wn = w & 3;

  const ushort_t* asrc[2][2];
  const ushort_t* bsrc[2][2];
  int sdst[2][2];
#pragma unroll
  for (int h = 0; h < 2; h++) {
#pragma unroll
    for (int j = 0; j < 2; j++) {
      int r = h * 128 + (w * 2 + j) * 8 + (lane >> 3);
      int cs = (lane & 7) ^ (r & 7);
      asrc[h][j] = Abase + (size_t)(m0 + r) * K + cs * 8;
      bsrc[h][j] = Bw + (size_t)(n0 + r) * K + cs * 8;
      sdst[h][j] = h * 16384 + (w * 2 + j) * 1024;
    }
  }

  f32x4 acc[8][4] = {};

#define DN_ST_A(p, h, k0)                                              \
  { char* _d = smem + (p) * 32768;                                     \
    gl_lds16(asrc[h][0] + (k0), _d + sdst[h][0]);                      \
    gl_lds16(asrc[h][1] + (k0), _d + sdst[h][1]); }
#define DN_ST_B(p, h, k0)                                              \
  { char* _d = smem + 65536 + (p) * 32768;                             \
    gl_lds16(bsrc[h][0] + (k0), _d + sdst[h][0]);                      \
    gl_lds16(bsrc[h][1] + (k0), _d + sdst[h][1]); }

  const int nt = K >> 6;
  DN_ST_A(0, 0, 0); DN_ST_A(0, 1, 0);
  DN_ST_B(0, 0, 0); DN_ST_B(0, 1, 0);
  DN_ST_B(1, 0, 64); DN_ST_B(1, 1, 64);
  asm volatile("s_waitcnt vmcnt(4)" ::: "memory");
  FENCE(); __builtin_amdgcn_s_barrier(); FENCE();

  short8 bfr[4][2];
  for (int t = 0; t < nt; t++) {
    int p = t & 1;
    const char* ab = smem + p * 32768;
    const char* bb = smem + 65536 + p * 32768;
    int k1 = (t + 1) * 64, k2 = (t + 2) * 64;
#pragma unroll
    for (int ph = 0; ph < 4; ph++) {
      if (ph == 0) {
#pragma unroll
        for (int n = 0; n < 4; n++) {
#pragma unroll
          for (int ks = 0; ks < 2; ks++) {
            int cc = wn * 64 + n * 16 + lr;
            bfr[n][ks] = *(const short8*)(bb + cc * 128 + ((ks * 64 + lk * 16) ^ ((cc & 7) << 4)));
          }
        }
      }
      short8 af[2][2];
#pragma unroll
      for (int m2 = 0; m2 < 2; m2++) {
#pragma unroll
        for (int ks = 0; ks < 2; ks++) {
          int rr = wm * 128 + ph * 32 + m2 * 16 + lr;
          af[m2][ks] = *(const short8*)(ab + rr * 128 + ((ks * 64 + lk * 16) ^ ((rr & 7) << 4)));
        }
      }
      if      (ph == 0) { if (t + 1 < nt) DN_ST_A(p ^ 1, 0, k1); }
      else if (ph == 1) { if (t + 1 < nt) DN_ST_A(p ^ 1, 1, k1); }
      else if (ph == 2) { if (t + 2 < nt) DN_ST_B(p, 0, k2); }
      else {
        if (t + 2 < nt) { DN_ST_B(p, 1, k2); asm volatile("s_waitcnt vmcnt(4)" ::: "memory"); }
        else            {                    asm volatile("s_waitcnt vmcnt(0)" ::: "memory"); }
      }
      FENCE(); __builtin_amdgcn_s_barrier(); FENCE();
      __builtin_amdgcn_s_setprio(1);
#pragma unroll
      for (int m2 = 0; m2 < 2; m2++) {
#pragma unroll
        for (int n = 0; n < 4; n++) {
#pragma unroll
          for (int ks = 0; ks < 2; ks++) {
            acc[ph * 2 + m2][n] = __builtin_amdgcn_mfma_f32_16x16x32_bf16(
                af[m2][ks], bfr[n][ks], acc[ph * 2 + m2][n], 0, 0, 0);
          }
        }
      }
      __builtin_amdgcn_s_setprio(0);
      FENCE(); __builtin_amdgcn_s_barrier(); FENCE();
    }
  }
#pragma unroll
  for (int m = 0; m < 8; m++) {
    int rowl = m0 + wm * 128 + m * 16 + lk * 4;
#pragma unroll
    for (int n = 0; n < 4; n++) {
      int col = n0 + wn * 64 + n * 16 + lr;
#pragma unroll
      for (int j = 0; j < 4; j++) {
        if (routed) {
          if (rowl + j < cnt) oe[(size_t)(gbase + rowl + j) * DH + col] = acc[m][n][j];
        } else {
          out[(size_t)(rowl + j) * DH + col] = acc[m][n][j];
        }
      }
    }
  }
}

// ---------------- combine ----------------
__global__ void combine_kernel(const int* __restrict__ tok_gslot,
                               const float* __restrict__ tok_w,
                               const float* __restrict__ oe,
                               float* __restrict__ out) {
  int t = blockIdx.x;
  int g1 = tok_gslot[2 * t], g2 = tok_gslot[2 * t + 1];
  float w1 = tok_w[2 * t], w2 = tok_w[2 * t + 1];
  int i = threadIdx.x * 8;
  const float4* p1 = (const float4*)(oe + (size_t)g1 * DH + i);
  const float4* p2 = (const float4*)(oe + (size_t)g2 * DH + i);
  float4* po = (float4*)(out + (size_t)t * DH + i);
  float4 a0 = p1[0], a1 = p1[1];
  float4 b0 = p2[0], b1 = p2[1];
  float4 o0 = po[0], o1 = po[1];
  o0.x += w1 * a0.x + w2 * b0.x;  o0.y += w1 * a0.y + w2 * b0.y;
  o0.z += w1 * a0.z + w2 * b0.z;  o0.w += w1 * a0.w + w2 * b0.w;
  o1.x += w1 * a1.x + w2 * b1.x;  o1.y += w1 * a1.y + w2 * b1.y;
  o1.z += w1 * a1.z + w2 * b1.z;  o1.w += w1 * a1.w + w2 * b1.w;
  po[0] = o0; po[1] = o1;
}

extern "C" void kernel_launch(void* const* d_in, const int* in_sizes, int n_in,
                              void* d_out, int out_size, void* d_ws, size_t ws_size,
                              hipStream_t stream) {
  const float* x    = (const float*)d_in[0];
  const float* gW   = (const float*)d_in[1];
  const float* Wg_e = (const float*)d_in[2];
  const float* Wu_e = (const float*)d_in[3];
  const float* Wd_e = (const float*)d_in[4];
  const float* Wg_s = (const float*)d_in[5];
  const float* Wu_s = (const float*)d_in[6];
  const float* Wd_s = (const float*)d_in[7];
  float* out = (float*)d_out;

  char* ws = (char*)d_ws;
  int*   counts   = (int*)ws;
  int*   ebase    = (int*)(ws + 64);
  int*   gu_off   = (int*)(ws + 128);
  int*   dn_off   = (int*)(ws + 192);
  int*   tok_e    = (int*)(ws + 256);
  int*   tok_slot = (int*)(ws + 256 + 16384);
  float* tok_w    = (float*)(ws + 256 + 32768);
  int*   slot2tok = (int*)(ws + 256 + 49152);
  ushort_t* xb  = (ushort_t*)(ws + 131072);
  ushort_t* h_r = (ushort_t*)(ws + 131072 + (size_t)T_TOK * DH * 2);
  ushort_t* h_s = h_r + (size_t)4096 * DE;
  float*    oe  = (float*)((char*)h_s + (size_t)T_TOK * DS * 2);
  ushort_t* wb  = (ushort_t*)((char*)oe + (size_t)4096 * DH * 4);
  ushort_t* wbg_e = wb;
  ushort_t* wbu_e = wb + NGEc;
  ushort_t* wbd_e = wb + 2 * NGEc;
  ushort_t* wbg_s = wb + 3 * NGEc;
  ushort_t* wbu_s = wbg_s + NGSc;
  ushort_t* wbd_s = wbg_s + 2 * NGSc;

  hipFuncSetAttribute((const void*)phaseB_kernel,
                      hipFuncAttributeMaxDynamicSharedMemorySize, 131072);
  hipFuncSetAttribute((const void*)down_kernel,
                      hipFuncAttributeMaxDynamicSharedMemorySize, 131072);

  hipMemsetAsync(counts, 0, 64, stream);
  phaseA_kernel<<<512 + PA_CVT_BLOCKS, 256, 0, stream>>>(
      x, gW, counts, tok_e, tok_slot, tok_w,
      Wg_e, Wu_e, Wg_s, Wu_s, wbg_e, wbu_e, wbg_s, wbu_s, xb);
  prefix_assign_kernel<<<1, 256, 0, stream>>>(counts, ebase, gu_off, dn_off,
                                              tok_e, tok_slot, slot2tok);
  phaseB_kernel<<<GU_NB + PB_CVT_BLOCKS, 512, 131072, stream>>>(
      xb, counts, ebase, gu_off, slot2tok, wbg_e, wbu_e, wbg_s, wbu_s, h_r, h_s,
      Wd_e, Wd_s, wbd_e, wbd_s);
  down_kernel<<<DN_NB, 512, 131072, stream>>>(
      h_r, h_s, counts, ebase, dn_off, wbd_e, wbd_s, oe, out);
  combine_kernel<<<T_TOK, 256, 0, stream>>>(tok_slot, tok_w, oe, out);
}

// Round 18
// 335.765 us; speedup vs baseline: 1.0539x; 1.0093x over previous
//
#include <hip/hip_runtime.h>

using short8 = __attribute__((ext_vector_type(8))) short;
using f32x4  = __attribute__((ext_vector_type(4))) float;
typedef unsigned short ushort_t;
typedef unsigned int u32;

#define T_TOK 2048
#define DH 2048
#define DE 1408
#define DS 2816
#define GU_NB 440   // gateup 256x128 tiles, multiple of 8
#define DN_NB 256   // down 256x256 tiles, multiple of 8

#define NGEc 23068672UL
#define NGSc 5767168UL
#define NXc  4194304UL
#define PA_CVT_BLOCKS 7552    // (2*NGE + 2*NGS + NX)/8192, 512 thr x 16 elems
#define PB_CVT_BLOCKS 7040

#define FENCE() asm volatile("" ::: "memory")

__device__ __forceinline__ unsigned short f2bf(float f) {
  unsigned u = __float_as_uint(f);
  u += 0x7FFF + ((u >> 16) & 1);
  return (unsigned short)(u >> 16);
}

__device__ __forceinline__ float bf2f(short v) {
  return __uint_as_float(((u32)(unsigned short)v) << 16);
}

__device__ __forceinline__ void gl_lds16(const void* g, void* l) {
  __builtin_amdgcn_global_load_lds((const __attribute__((address_space(1))) u32*)g,
                                   (__attribute__((address_space(3))) u32*)l, 16, 0, 0);
}

__device__ __forceinline__ short8 pack_bf8(float4 a, float4 b) {
  short8 o;
  o[0] = (short)f2bf(a.x); o[1] = (short)f2bf(a.y);
  o[2] = (short)f2bf(a.z); o[3] = (short)f2bf(a.w);
  o[4] = (short)f2bf(b.x); o[5] = (short)f2bf(b.y);
  o[6] = (short)f2bf(b.z); o[7] = (short)f2bf(b.w);
  return o;
}

// ---------------- phase A: router (256 blocks x 8 waves) || cvt 16 elems/thread ----------------
__global__ void phaseA_kernel(const float* __restrict__ x, const float* __restrict__ gW,
                              int* __restrict__ counts, int* __restrict__ tok_e,
                              int* __restrict__ tok_slot, float* __restrict__ tok_w,
                              const float* __restrict__ Wg_e, const float* __restrict__ Wu_e,
                              const float* __restrict__ Wg_s, const float* __restrict__ Wu_s,
                              ushort_t* wbg_e, ushort_t* wbu_e,
                              ushort_t* wbg_s, ushort_t* wbu_s, ushort_t* xb) {
  int b = blockIdx.x;
  int tid = threadIdx.x;
  if (b < 256) {
    int wid = tid >> 6, lane = tid & 63;
    int t = b * 8 + wid;
    float acc[8] = {0.f,0.f,0.f,0.f,0.f,0.f,0.f,0.f};
    const float* xt = x + (size_t)t * DH;
    for (int i = lane; i < DH; i += 64) {
      float xv = xt[i];
#pragma unroll
      for (int e = 0; e < 8; e++) acc[e] += xv * gW[e * DH + i];
    }
#pragma unroll
    for (int e = 0; e < 8; e++) {
#pragma unroll
      for (int off = 32; off > 0; off >>= 1) acc[e] += __shfl_xor(acc[e], off);
    }
    if (lane == 0) {
      float mx = acc[0];
      for (int e = 1; e < 8; e++) mx = fmaxf(mx, acc[e]);
      float p[8], se = 0.f;
      for (int e = 0; e < 8; e++) { p[e] = __expf(acc[e] - mx); se += p[e]; }
      for (int e = 0; e < 8; e++) p[e] /= se;
      int i1 = 0;
      for (int e = 1; e < 8; e++) if (p[e] > p[i1]) i1 = e;
      int i2 = (i1 == 0) ? 1 : 0;
      for (int e = 0; e < 8; e++) if (e != i1 && p[e] > p[i2]) i2 = e;
      int s1 = atomicAdd(&counts[i1], 1);
      int s2 = atomicAdd(&counts[i2], 1);
      tok_e[2 * t] = i1;     tok_e[2 * t + 1] = i2;
      tok_slot[2 * t] = s1;  tok_slot[2 * t + 1] = s2;
      tok_w[2 * t] = p[i1];  tok_w[2 * t + 1] = p[i2];
    }
    return;
  }
  // cvt: 16 elems/thread; all tensor boundaries are multiples of 8192
  size_t i = (size_t)(b - 256) * 8192 + (size_t)tid * 16;
  const float* s; ushort_t* d; size_t o;
  if      (i < NGEc)                    { s = Wg_e; d = wbg_e; o = i; }
  else if (i < 2 * NGEc)                { s = Wu_e; d = wbu_e; o = i - NGEc; }
  else if (i < 2 * NGEc + NGSc)         { s = Wg_s; d = wbg_s; o = i - 2 * NGEc; }
  else if (i < 2 * NGEc + 2 * NGSc)     { s = Wu_s; d = wbu_s; o = i - 2 * NGEc - NGSc; }
  else                                  { s = x;    d = xb;    o = i - 2 * NGEc - 2 * NGSc; }
  float4 a0 = *(const float4*)(s + o);
  float4 b0 = *(const float4*)(s + o + 4);
  float4 a1 = *(const float4*)(s + o + 8);
  float4 b1 = *(const float4*)(s + o + 12);
  *(short8*)(d + o)     = pack_bf8(a0, b0);
  *(short8*)(d + o + 8) = pack_bf8(a1, b1);
}

// ---------------- prefix ----------------
__global__ void prefix_assign_kernel(const int* __restrict__ counts, int* __restrict__ ebase,
                                     int* __restrict__ gu_off, int* __restrict__ dn_off,
                                     const int* __restrict__ tok_e, int* __restrict__ tok_slot,
                                     int* __restrict__ slot2tok) {
  __shared__ int sbase[8];
  if (threadIdx.x == 0) {
    int a = 0;
    for (int e = 0; e < 8; e++) { sbase[e] = a; ebase[e] = a; a += counts[e]; }
    int g = 0, d = 0;
    for (int z = 0; z < 8; z++) {
      gu_off[z] = g; dn_off[z] = d;
      int Lg = (counts[z] + 255) >> 8;
      g += Lg * 11;
      int Ld = (counts[z] + 255) >> 8;
      d += Ld * 8;
    }
    gu_off[8] = g; g += 88;
    gu_off[9] = g; g += 88;
    gu_off[10] = g;
    dn_off[8] = d; d += 64;
    dn_off[9] = d;
  }
  __syncthreads();
  for (int idx = threadIdx.x; idx < T_TOK * 2; idx += blockDim.x) {
    int e = tok_e[idx];
    int g = sbase[e] + tok_slot[idx];
    tok_slot[idx] = g;
    slot2tok[g] = idx >> 1;
  }
}

// ---------------- phase B: gateup 256x128 8-wave 2-phase || cvt Wd ----------------
__global__ __launch_bounds__(512, 1) void phaseB_kernel(
    const ushort_t* __restrict__ xb, const int* __restrict__ counts,
    const int* __restrict__ ebase, const int* __restrict__ gu_off,
    const int* __restrict__ slot2tok,
    const ushort_t* __restrict__ Wbg_e, const ushort_t* __restrict__ Wbu_e,
    const ushort_t* __restrict__ Wbg_s, const ushort_t* __restrict__ Wbu_s,
    ushort_t* __restrict__ h_r, ushort_t* __restrict__ h_s,
    const float* __restrict__ Wd_e, const float* __restrict__ Wd_s,
    ushort_t* wbd_e, ushort_t* wbd_s) {
  extern __shared__ char smem[];   // 128KB: A[2][32K] @0 | Bg[2][16K] @64K | Bu[2][16K] @96K
  int tid = threadIdx.x;
  if (blockIdx.x >= GU_NB) {
    size_t i = (size_t)(blockIdx.x - GU_NB) * 4096 + (size_t)tid * 8;
    const float* s; ushort_t* d; size_t o;
    if (i < NGEc) { s = Wd_e; d = wbd_e; o = i; }
    else          { s = Wd_s; d = wbd_s; o = i - NGEc; }
    float4 a = *(const float4*)(s + o);
    float4 bb = *(const float4*)(s + o + 4);
    *(short8*)(d + o) = pack_bf8(a, bb);
    return;
  }
  int b = blockIdx.x;
  int c = (b & 7) * (GU_NB >> 3) + (b >> 3);
  int off[11];
#pragma unroll
  for (int zz = 0; zz < 11; zz++) off[zz] = gu_off[zz];
  if (c >= off[10]) return;
  int z = 0;
#pragma unroll
  for (int zz = 1; zz < 10; zz++) if (c >= off[zz]) z = zz;
  int cz = c - off[z];

  bool routed = (z < 8);
  int cnt, gbase, Lm;
  const ushort_t *Bg, *Bu;
  if (routed) {
    cnt = counts[z]; gbase = ebase[z];
    Lm = (cnt + 255) >> 8;
    Bg = Wbg_e + (size_t)z * DE * DH;
    Bu = Wbu_e + (size_t)z * DE * DH;
  } else {
    cnt = T_TOK; gbase = 0; Lm = 8;
    Bg = Wbg_s + (size_t)(z - 8) * 1408 * DH;
    Bu = Wbu_s + (size_t)(z - 8) * 1408 * DH;
  }
  int mt = cz % Lm, y = cz / Lm;
  int m0 = mt * 256, n0 = y * 128;

  int lane = tid & 63, w = tid >> 6;
  int lr = lane & 15, lk = lane >> 4;
  int wm = w >> 1, wn = w & 1;

  const ushort_t* asrc[4];
  int adst[4];
#pragma unroll
  for (int j = 0; j < 4; j++) {
    int r = (w * 4 + j) * 8 + (lane >> 3);
    int lrow = m0 + r;
    int tok = routed ? ((lrow < cnt) ? slot2tok[gbase + lrow] : 0) : lrow;
    int cs = (lane & 7) ^ (r & 7);
    asrc[j] = xb + (size_t)tok * DH + cs * 8;
    adst[j] = (w * 4 + j) * 1024;
  }
  const ushort_t* gsrc[2];
  const ushort_t* usrc[2];
  int wdst[2];
#pragma unroll
  for (int j = 0; j < 2; j++) {
    int r = (w * 2 + j) * 8 + (lane >> 3);
    int cs = (lane & 7) ^ (r & 7);
    gsrc[j] = Bg + (size_t)(n0 + r) * DH + cs * 8;
    usrc[j] = Bu + (size_t)(n0 + r) * DH + cs * 8;
    wdst[j] = (w * 2 + j) * 1024;
  }

  f32x4 accg[4][4] = {};
  f32x4 accu[4][4] = {};

#define GU_STAGE(buf, k0)                                             \
  {                                                                   \
    char* ab = smem + (buf) * 32768;                                  \
    char* gb = smem + 65536 + (buf) * 16384;                          \
    char* ub = smem + 98304 + (buf) * 16384;                          \
    _Pragma("unroll")                                                 \
    for (int j = 0; j < 4; j++) gl_lds16(asrc[j] + (k0), ab + adst[j]); \
    _Pragma("unroll")                                                 \
    for (int j = 0; j < 2; j++) {                                     \
      gl_lds16(gsrc[j] + (k0), gb + wdst[j]);                         \
      gl_lds16(usrc[j] + (k0), ub + wdst[j]);                         \
    }                                                                 \
  }

  const int nt = DH >> 6;   // 32
  GU_STAGE(0, 0);
  __syncthreads();
  int cur = 0;
  for (int t = 0; t < nt; t++) {
    if (t + 1 < nt) GU_STAGE(cur ^ 1, (t + 1) * 64);
    const char* ab = smem + cur * 32768;
    const char* gb = smem + 65536 + cur * 16384;
    const char* ub = smem + 98304 + cur * 16384;
    short8 af[4][2], bg[4][2], bu[4][2];
#pragma unroll
    for (int m = 0; m < 4; m++) {
#pragma unroll
      for (int ks = 0; ks < 2; ks++) {
        int rr = wm * 64 + m * 16 + lr;
        af[m][ks] = *(const short8*)(ab + rr * 128 + ((ks * 64 + lk * 16) ^ ((rr & 7) << 4)));
      }
    }
#pragma unroll
    for (int n = 0; n < 4; n++) {
#pragma unroll
      for (int ks = 0; ks < 2; ks++) {
        int cc = wn * 64 + n * 16 + lr;
        bg[n][ks] = *(const short8*)(gb + cc * 128 + ((ks * 64 + lk * 16) ^ ((cc & 7) << 4)));
        bu[n][ks] = *(const short8*)(ub + cc * 128 + ((ks * 64 + lk * 16) ^ ((cc & 7) << 4)));
      }
    }
    __builtin_amdgcn_s_setprio(1);
#pragma unroll
    for (int m = 0; m < 4; m++) {
#pragma unroll
      for (int n = 0; n < 4; n++) {
#pragma unroll
        for (int ks = 0; ks < 2; ks++) {
          accg[m][n] = __builtin_amdgcn_mfma_f32_16x16x32_bf16(af[m][ks], bg[n][ks], accg[m][n], 0, 0, 0);
          accu[m][n] = __builtin_amdgcn_mfma_f32_16x16x32_bf16(af[m][ks], bu[n][ks], accu[m][n], 0, 0, 0);
        }
      }
    }
    __builtin_amdgcn_s_setprio(0);
    __syncthreads();
    cur ^= 1;
  }
#pragma unroll
  for (int m = 0; m < 4; m++) {
    int rowl = m0 + wm * 64 + m * 16 + lk * 4;
#pragma unroll
    for (int n = 0; n < 4; n++) {
      int col = n0 + wn * 64 + n * 16 + lr;
#pragma unroll
      for (int j = 0; j < 4; j++) {
        float g = accg[m][n][j], u = accu[m][n][j];
        float s = g / (1.f + __expf(-g));
        unsigned short hv = f2bf(s * u);
        if (routed) {
          if (rowl + j < cnt) h_r[(size_t)(gbase + rowl + j) * DE + col] = hv;
        } else {
          h_s[(size_t)(rowl + j) * DS + (z - 8) * 1408 + col] = hv;
        }
      }
    }
  }
}

// ---------------- down: 256x256, 8-wave, 8-phase counted-vmcnt; oe in bf16 ----------------
__global__ __launch_bounds__(512, 1) void down_kernel(
    const ushort_t* __restrict__ h_r, const ushort_t* __restrict__ h_s,
    const int* __restrict__ counts, const int* __restrict__ ebase,
    const int* __restrict__ dn_off,
    const ushort_t* __restrict__ Wbd_e, const ushort_t* __restrict__ Wbd_s,
    ushort_t* __restrict__ oe, float* __restrict__ out) {
  extern __shared__ char smem[];   // 128KB: A[2buf][2half][16K] @0 | B[2buf][2half][16K] @64K

  int b = blockIdx.x;
  int c = (b & 7) * (DN_NB >> 3) + (b >> 3);
  int off[10];
#pragma unroll
  for (int zz = 0; zz < 10; zz++) off[zz] = dn_off[zz];
  if (c >= off[9]) return;
  int z = 0;
#pragma unroll
  for (int zz = 1; zz < 9; zz++) if (c >= off[zz]) z = zz;
  int cz = c - off[z];

  bool routed = (z < 8);
  int cnt, gbase, K, Lm;
  const ushort_t* Abase;
  const ushort_t* Bw;
  if (routed) {
    cnt = counts[z]; gbase = ebase[z];
    Lm = (cnt + 255) >> 8;
    K = DE;
    Abase = h_r + (size_t)gbase * DE;
    Bw = Wbd_e + (size_t)z * DH * DE;
  } else {
    cnt = T_TOK; gbase = 0; Lm = 8;
    K = DS;
    Abase = h_s;
    Bw = Wbd_s;
  }
  int mt = cz % Lm, y = cz / Lm;
  int m0 = mt * 256, n0 = y * 256;

  int tid = threadIdx.x;
  int lane = tid & 63, w = tid >> 6;
  int lr = lane & 15, lk = lane >> 4;
  int wm = w >> 2, wn = w & 3;

  const ushort_t* asrc[2][2];
  const ushort_t* bsrc[2][2];
  int sdst[2][2];
#pragma unroll
  for (int h = 0; h < 2; h++) {
#pragma unroll
    for (int j = 0; j < 2; j++) {
      int r = h * 128 + (w * 2 + j) * 8 + (lane >> 3);
      int cs = (lane & 7) ^ (r & 7);
      asrc[h][j] = Abase + (size_t)(m0 + r) * K + cs * 8;
      bsrc[h][j] = Bw + (size_t)(n0 + r) * K + cs * 8;
      sdst[h][j] = h * 16384 + (w * 2 + j) * 1024;
    }
  }

  f32x4 acc[8][4] = {};

#define DN_ST_A(p, h, k0)                                              \
  { char* _d = smem + (p) * 32768;                                     \
    gl_lds16(asrc[h][0] + (k0), _d + sdst[h][0]);                      \
    gl_lds16(asrc[h][1] + (k0), _d + sdst[h][1]); }
#define DN_ST_B(p, h, k0)                                              \
  { char* _d = smem + 65536 + (p) * 32768;                             \
    gl_lds16(bsrc[h][0] + (k0), _d + sdst[h][0]);                      \
    gl_lds16(bsrc[h][1] + (k0), _d + sdst[h][1]); }

  const int nt = K >> 6;
  DN_ST_A(0, 0, 0); DN_ST_A(0, 1, 0);
  DN_ST_B(0, 0, 0); DN_ST_B(0, 1, 0);
  DN_ST_B(1, 0, 64); DN_ST_B(1, 1, 64);
  asm volatile("s_waitcnt vmcnt(4)" ::: "memory");
  FENCE(); __builtin_amdgcn_s_barrier(); FENCE();

  short8 bfr[4][2];
  for (int t = 0; t < nt; t++) {
    int p = t & 1;
    const char* ab = smem + p * 32768;
    const char* bb = smem + 65536 + p * 32768;
    int k1 = (t + 1) * 64, k2 = (t + 2) * 64;
#pragma unroll
    for (int ph = 0; ph < 4; ph++) {
      if (ph == 0) {
#pragma unroll
        for (int n = 0; n < 4; n++) {
#pragma unroll
          for (int ks = 0; ks < 2; ks++) {
            int cc = wn * 64 + n * 16 + lr;
            bfr[n][ks] = *(const short8*)(bb + cc * 128 + ((ks * 64 + lk * 16) ^ ((cc & 7) << 4)));
          }
        }
      }
      short8 af[2][2];
#pragma unroll
      for (int m2 = 0; m2 < 2; m2++) {
#pragma unroll
        for (int ks = 0; ks < 2; ks++) {
          int rr = wm * 128 + ph * 32 + m2 * 16 + lr;
          af[m2][ks] = *(const short8*)(ab + rr * 128 + ((ks * 64 + lk * 16) ^ ((rr & 7) << 4)));
        }
      }
      if      (ph == 0) { if (t + 1 < nt) DN_ST_A(p ^ 1, 0, k1); }
      else if (ph == 1) { if (t + 1 < nt) DN_ST_A(p ^ 1, 1, k1); }
      else if (ph == 2) { if (t + 2 < nt) DN_ST_B(p, 0, k2); }
      else {
        if (t + 2 < nt) { DN_ST_B(p, 1, k2); asm volatile("s_waitcnt vmcnt(4)" ::: "memory"); }
        else            {                    asm volatile("s_waitcnt vmcnt(0)" ::: "memory"); }
      }
      FENCE(); __builtin_amdgcn_s_barrier(); FENCE();
      __builtin_amdgcn_s_setprio(1);
#pragma unroll
      for (int m2 = 0; m2 < 2; m2++) {
#pragma unroll
        for (int n = 0; n < 4; n++) {
#pragma unroll
          for (int ks = 0; ks < 2; ks++) {
            acc[ph * 2 + m2][n] = __builtin_amdgcn_mfma_f32_16x16x32_bf16(
                af[m2][ks], bfr[n][ks], acc[ph * 2 + m2][n], 0, 0, 0);
          }
        }
      }
      __builtin_amdgcn_s_setprio(0);
      FENCE(); __builtin_amdgcn_s_barrier(); FENCE();
    }
  }
#pragma unroll
  for (int m = 0; m < 8; m++) {
    int rowl = m0 + wm * 128 + m * 16 + lk * 4;
#pragma unroll
    for (int n = 0; n < 4; n++) {
      int col = n0 + wn * 64 + n * 16 + lr;
#pragma unroll
      for (int j = 0; j < 4; j++) {
        if (routed) {
          if (rowl + j < cnt)
            oe[(size_t)(gbase + rowl + j) * DH + col] = f2bf(acc[m][n][j]);
        } else {
          out[(size_t)(rowl + j) * DH + col] = acc[m][n][j];
        }
      }
    }
  }
}

// ---------------- combine: out[t] += w1*oe[g1] + w2*oe[g2]  (oe bf16) ----------------
__global__ void combine_kernel(const int* __restrict__ tok_gslot,
                               const float* __restrict__ tok_w,
                               const ushort_t* __restrict__ oe,
                               float* __restrict__ out) {
  int t = blockIdx.x;
  int g1 = tok_gslot[2 * t], g2 = tok_gslot[2 * t + 1];
  float w1 = tok_w[2 * t], w2 = tok_w[2 * t + 1];
  int i = threadIdx.x * 8;
  short8 a = *(const short8*)(oe + (size_t)g1 * DH + i);
  short8 b = *(const short8*)(oe + (size_t)g2 * DH + i);
  float4* po = (float4*)(out + (size_t)t * DH + i);
  float4 o0 = po[0], o1 = po[1];
  o0.x += w1 * bf2f(a[0]) + w2 * bf2f(b[0]);
  o0.y += w1 * bf2f(a[1]) + w2 * bf2f(b[1]);
  o0.z += w1 * bf2f(a[2]) + w2 * bf2f(b[2]);
  o0.w += w1 * bf2f(a[3]) + w2 * bf2f(b[3]);
  o1.x += w1 * bf2f(a[4]) + w2 * bf2f(b[4]);
  o1.y += w1 * bf2f(a[5]) + w2 * bf2f(b[5]);
  o1.z += w1 * bf2f(a[6]) + w2 * bf2f(b[6]);
  o1.w += w1 * bf2f(a[7]) + w2 * bf2f(b[7]);
  po[0] = o0; po[1] = o1;
}

extern "C" void kernel_launch(void* const* d_in, const int* in_sizes, int n_in,
                              void* d_out, int out_size, void* d_ws, size_t ws_size,
                              hipStream_t stream) {
  const float* x    = (const float*)d_in[0];
  const float* gW   = (const float*)d_in[1];
  const float* Wg_e = (const float*)d_in[2];
  const float* Wu_e = (const float*)d_in[3];
  const float* Wd_e = (const float*)d_in[4];
  const float* Wg_s = (const float*)d_in[5];
  const float* Wu_s = (const float*)d_in[6];
  const float* Wd_s = (const float*)d_in[7];
  float* out = (float*)d_out;

  char* ws = (char*)d_ws;
  int*   counts   = (int*)ws;
  int*   ebase    = (int*)(ws + 64);
  int*   gu_off   = (int*)(ws + 128);
  int*   dn_off   = (int*)(ws + 192);
  int*   tok_e    = (int*)(ws + 256);
  int*   tok_slot = (int*)(ws + 256 + 16384);
  float* tok_w    = (float*)(ws + 256 + 32768);
  int*   slot2tok = (int*)(ws + 256 + 49152);
  ushort_t* xb  = (ushort_t*)(ws + 131072);
  ushort_t* h_r = (ushort_t*)(ws + 131072 + (size_t)T_TOK * DH * 2);
  ushort_t* h_s = h_r + (size_t)4096 * DE;
  ushort_t* oe  = (ushort_t*)((char*)h_s + (size_t)T_TOK * DS * 2);   // bf16, region still reserves 32MB
  ushort_t* wb  = (ushort_t*)((char*)oe + (size_t)4096 * DH * 4);
  ushort_t* wbg_e = wb;
  ushort_t* wbu_e = wb + NGEc;
  ushort_t* wbd_e = wb + 2 * NGEc;
  ushort_t* wbg_s = wb + 3 * NGEc;
  ushort_t* wbu_s = wbg_s + NGSc;
  ushort_t* wbd_s = wbg_s + 2 * NGSc;

  hipFuncSetAttribute((const void*)phaseB_kernel,
                      hipFuncAttributeMaxDynamicSharedMemorySize, 131072);
  hipFuncSetAttribute((const void*)down_kernel,
                      hipFuncAttributeMaxDynamicSharedMemorySize, 131072);

  hipMemsetAsync(counts, 0, 64, stream);
  phaseA_kernel<<<256 + PA_CVT_BLOCKS, 512, 0, stream>>>(
      x, gW, counts, tok_e, tok_slot, tok_w,
      Wg_e, Wu_e, Wg_s, Wu_s, wbg_e, wbu_e, wbg_s, wbu_s, xb);
  prefix_assign_kernel<<<1, 256, 0, stream>>>(counts, ebase, gu_off, dn_off,
                                              tok_e, tok_slot, slot2tok);
  phaseB_kernel<<<GU_NB + PB_CVT_BLOCKS, 512, 131072, stream>>>(
      xb, counts, ebase, gu_off, slot2tok, wbg_e, wbu_e, wbg_s, wbu_s, h_r, h_s,
      Wd_e, Wd_s, wbd_e, wbd_s);
  down_kernel<<<DN_NB, 512, 131072, stream>>>(
      h_r, h_s, counts, ebase, dn_off, wbd_e, wbd_s, oe, out);
  combine_kernel<<<T_TOK, 256, 0, stream>>>(tok_slot, tok_w, oe, out);
}